// Round 7
// baseline (416.036 us; speedup 1.0000x reference)
//
#include <hip/hip_runtime.h>
#include <hip/hip_fp16.h>
#include <math.h>
#include <string.h>

// GAT 2-layer, N=100000, E=1600000, F_IN=128, HID=128 (H=4,C=32), OUT=64 (H=1,C=64)
// R6 -> R7: evidence says aggregation is bound by the L2-miss fetch path
// (~3.1 TB/s across R1/R3/R4/R6). aggregate1 now runs as TWO sequential
// half-channel passes: each gathers 128B half-rows from a 12.8MB footprint
// (vs 25.6MB) to lift the per-XCD L2 hit rate. CSR rec packed into one uint
// (src | dst_low9 << 17), halving rec traffic. agg2 unchanged (12.8MB set).

#define BSH 9      // log2 dsts per bucket
#define DPB 512    // dsts per bucket
#define NBK 256    // max buckets (covers N < 131072)
#define CH1 16384  // edges per block in bucket_scatter
#define LOG2E 1.44269504088896f

__device__ __forceinline__ float exp2_fast(float x) {
#if __has_builtin(__builtin_amdgcn_exp2f)
    return __builtin_amdgcn_exp2f(x);
#else
    return exp2f(x);
#endif
}

// ---------------- CSR build: bucketed counting sort ----------------

__global__ __launch_bounds__(256) void bucket_hist(const int* __restrict__ ei, int E, int N,
                                                   unsigned* __restrict__ bcount) {
    __shared__ unsigned hist[NBK];
    int t = threadIdx.x;
    hist[t] = 0;
    __syncthreads();
    int Etot = E + N;
    for (int k = blockIdx.x * 256 + t; k < Etot; k += gridDim.x * 256) {
        int d = (k < E) ? ei[E + k] : (k - E);
        atomicAdd(&hist[d >> BSH], 1u);
    }
    __syncthreads();
    unsigned c = hist[t];
    if (c) atomicAdd(&bcount[t], c);
}

__global__ void scan_buckets(const unsigned* __restrict__ bcount, unsigned* __restrict__ bbase,
                             unsigned* __restrict__ bcursor) {
    __shared__ unsigned s[NBK];
    int t = threadIdx.x;
    unsigned v = bcount[t];
    s[t] = v;
    __syncthreads();
    for (int o = 1; o < NBK; o <<= 1) {
        unsigned add = (t >= o) ? s[t - o] : 0;
        __syncthreads();
        s[t] += add;
        __syncthreads();
    }
    unsigned excl = s[t] - v;
    bbase[t] = excl;
    bcursor[t] = excl;
    if (t == NBK - 1) bbase[NBK] = excl + v;   // = Etot
}

// rec word: src in bits [0,17), dst low 9 bits in [17,26)
__global__ __launch_bounds__(256) void bucket_scatter(const int* __restrict__ ei, int E, int N,
                                                      unsigned* __restrict__ bcursor,
                                                      unsigned* __restrict__ rec) {
    __shared__ unsigned hist[NBK];
    __shared__ unsigned base[NBK];
    int t = threadIdx.x;
    hist[t] = 0;
    __syncthreads();
    int Etot = E + N;
    int k0 = blockIdx.x * CH1;
    int k1 = min(k0 + CH1, Etot);
    for (int k = k0 + t; k < k1; k += 256) {
        int d = (k < E) ? ei[E + k] : (k - E);
        atomicAdd(&hist[d >> BSH], 1u);
    }
    __syncthreads();
    unsigned c = hist[t];
    base[t] = c ? atomicAdd(&bcursor[t], c) : 0u;
    hist[t] = 0;
    __syncthreads();
    for (int k = k0 + t; k < k1; k += 256) {
        int s, d;
        if (k < E) { s = ei[k]; d = ei[E + k]; } else { s = d = k - E; }
        int b = d >> BSH;
        unsigned r = atomicAdd(&hist[b], 1u);
        rec[base[b] + r] = (unsigned)s | ((unsigned)(d & (DPB - 1)) << 17);
    }
}

__global__ __launch_bounds__(256) void bucket_sort(const unsigned* __restrict__ rec,
                                                   const unsigned* __restrict__ bbase,
                                                   int* __restrict__ offs, int* __restrict__ srcs,
                                                   int N, int Etot) {
    __shared__ unsigned hist[DPB];
    __shared__ unsigned tsum[256];
    int t = threadIdx.x, bb = blockIdx.x;
    unsigned r0 = bbase[bb], r1 = bbase[bb + 1];
    hist[t] = 0;
    hist[t + 256] = 0;
    __syncthreads();
    int dlo = bb << BSH;
    for (unsigned k = r0 + t; k < r1; k += 256) {
        unsigned e = rec[k];
        atomicAdd(&hist[e >> 17], 1u);
    }
    __syncthreads();
    unsigned h0 = hist[2 * t], h1 = hist[2 * t + 1];
    tsum[t] = h0 + h1;
    __syncthreads();
    for (int o = 1; o < 256; o <<= 1) {
        unsigned a = (t >= o) ? tsum[t - o] : 0;
        __syncthreads();
        tsum[t] += a;
        __syncthreads();
    }
    unsigned tb = tsum[t] - (h0 + h1);
    int d0 = dlo + 2 * t;
    if (d0 < N) offs[d0] = (int)(r0 + tb);
    if (d0 + 1 < N) offs[d0 + 1] = (int)(r0 + tb + h0);
    hist[2 * t] = tb;            // reuse as relative cursors
    hist[2 * t + 1] = tb + h0;
    __syncthreads();
    for (unsigned k = r0 + t; k < r1; k += 256) {
        unsigned e = rec[k];
        unsigned r = atomicAdd(&hist[e >> 17], 1u);
        srcs[r0 + r] = (int)(e & 0x1FFFFu);
    }
    if (bb == 0 && t == 0) offs[N] = Etot;
}

// ---------------- GEMM + fused alphas: C[M,NC] = A[M,128] * B[128,NC] ----------------

template <int NC, int H, typename InT, typename OutT>
__global__ __launch_bounds__(256) void gemm_k128(const InT* __restrict__ A,
                                                 const float* __restrict__ B,
                                                 OutT* __restrict__ C,
                                                 const float* __restrict__ a_src,
                                                 const float* __restrict__ a_dst,
                                                 float* __restrict__ as,
                                                 float* __restrict__ ad, int M) {
    constexpr int BM = 64, BK = 32, K = 128;
    constexpr int TPR = NC / 4;          // threads covering NC cols via 4-col groups
    constexpr int R = BM / (256 / TPR);  // rows per thread (8 or 4)
    constexpr int TXH = TPR / H;         // tx lanes per head
    __shared__ float AsT[BK][BM + 4];    // +4 pad: breaks 16-way bank conflict on transpose store
    __shared__ float Bs[BK][NC];
    int tid = threadIdx.x;
    int tx = tid % TPR, ty = tid / TPR;
    int rowBase = blockIdx.x * BM;
    float acc[R][4] = {};
    for (int k0 = 0; k0 < K; k0 += BK) {
#pragma unroll
        for (int i = 0; i < 4; ++i) {
            int lin = tid + i * 256;     // 0..1023 2-elem slots
            int row = lin >> 4;          // 16 slots per row
            int kp = lin & 15;
            int grow = rowBase + row;
            if (grow >= M) grow = M - 1;
            float2 v;
            if constexpr (sizeof(InT) == 2) {
                __half2 hv = *reinterpret_cast<const __half2*>((const __half*)A + (size_t)grow * K + k0 + kp * 2);
                v = __half22float2(hv);
            } else {
                v = *reinterpret_cast<const float2*>((const float*)A + (size_t)grow * K + k0 + kp * 2);
            }
            AsT[kp * 2][row] = v.x;
            AsT[kp * 2 + 1][row] = v.y;
        }
#pragma unroll
        for (int i = 0; i < (BK * NC) / 1024; ++i) {
            int lin = tid + i * 256;     // float4 index
            int row = lin / (NC / 4);
            int col4 = lin % (NC / 4);
            float4 v = *reinterpret_cast<const float4*>(B + (size_t)(k0 + row) * NC + col4 * 4);
            *reinterpret_cast<float4*>(&Bs[row][col4 * 4]) = v;
        }
        __syncthreads();
#pragma unroll
        for (int kk = 0; kk < BK; ++kk) {
            float4 bv = *reinterpret_cast<const float4*>(&Bs[kk][tx * 4]);
            float a[R];
#pragma unroll
            for (int r4 = 0; r4 < R; r4 += 4) {
                float4 av = *reinterpret_cast<const float4*>(&AsT[kk][ty * R + r4]);
                a[r4] = av.x; a[r4 + 1] = av.y; a[r4 + 2] = av.z; a[r4 + 3] = av.w;
            }
#pragma unroll
            for (int r = 0; r < R; ++r) {
                acc[r][0] = fmaf(a[r], bv.x, acc[r][0]);
                acc[r][1] = fmaf(a[r], bv.y, acc[r][1]);
                acc[r][2] = fmaf(a[r], bv.z, acc[r][2]);
                acc[r][3] = fmaf(a[r], bv.w, acc[r][3]);
            }
        }
        __syncthreads();
    }
    // C store + fused alpha epilogue
    float4 asv = *reinterpret_cast<const float4*>(a_src + tx * 4);
    float4 adv = *reinterpret_cast<const float4*>(a_dst + tx * 4);
#pragma unroll
    for (int r = 0; r < R; ++r) {
        int grow = rowBase + ty * R + r;
        bool live = grow < M;
        if (live) {
            if constexpr (sizeof(OutT) == 2) {
                __half2 p0 = __floats2half2_rn(acc[r][0], acc[r][1]);
                __half2 p1 = __floats2half2_rn(acc[r][2], acc[r][3]);
                __half2* cp = reinterpret_cast<__half2*>((__half*)C + (size_t)grow * NC + tx * 4);
                cp[0] = p0;
                cp[1] = p1;
            } else {
                float4 v = make_float4(acc[r][0], acc[r][1], acc[r][2], acc[r][3]);
                *reinterpret_cast<float4*>((float*)C + (size_t)grow * NC + tx * 4) = v;
            }
        }
        float ps = acc[r][0] * asv.x + acc[r][1] * asv.y + acc[r][2] * asv.z + acc[r][3] * asv.w;
        float pd = acc[r][0] * adv.x + acc[r][1] * adv.y + acc[r][2] * adv.z + acc[r][3] * adv.w;
#pragma unroll
        for (int o = 1; o < TXH; o <<= 1) {
            ps += __shfl_xor(ps, o, 64);
            pd += __shfl_xor(pd, o, 64);
        }
        if ((tx & (TXH - 1)) == 0 && live) {
            int head = tx / TXH;
            as[(size_t)grow * H + head] = ps * LOG2E;
            ad[(size_t)grow * H + head] = pd * LOG2E;
        }
    }
}

// ---------------- aggregation: 4 dst nodes per wave, 16 lanes per node ----------------
// ROWS = h row length (and out row stride); COFF = first channel this pass;
// CW = channels this pass (spread over 16 lanes). as/ad in log2 domain.

template <int H, int ROWS, int COFF, int CW, bool DOELU, typename OutT>
__global__ __launch_bounds__(256) void aggregateQ(const __half* __restrict__ h,
                                                  const float* __restrict__ as,
                                                  const float* __restrict__ ad,
                                                  const int* __restrict__ offs,
                                                  const int* __restrict__ srcs,
                                                  const float* __restrict__ bias,
                                                  OutT* __restrict__ out, int N) {
    constexpr int CPL = CW / 16;    // channels per lane (4 or 8)
    constexpr int NH2 = CPL / 2;    // half2 per lane
    unsigned wave = (blockIdx.x * blockDim.x + threadIdx.x) >> 6;
    unsigned lane = threadIdx.x & 63;
    unsigned lig = lane & 15;       // lane in group
    unsigned node = wave * 4u + (lane >> 4);
    bool live = node < (unsigned)N;
    unsigned nc = live ? node : (unsigned)(N - 1);
    unsigned chan = COFF + lig * CPL;        // first channel owned by this lane
    unsigned head = (chan * H) / ROWS;
    float adv = ad[nc * H + head];
    int e0 = offs[nc], e1 = offs[nc + 1];
    int deg = e1 - e0, e1m1 = e1 - 1;
    int md = deg;
    md = max(md, __shfl_xor(md, 16, 64));
    md = max(md, __shfl_xor(md, 32, 64));
    float2 acc[NH2] = {};
    float den = 0.f;
    for (int k = 0; k < md; k += 2) {
        unsigned ja = (unsigned)srcs[min(e0 + k, e1m1)];
        unsigned jb = (unsigned)srcs[min(e0 + k + 1, e1m1)];
        float ta = as[ja * H + head] + adv;
        float tb = as[jb * H + head] + adv;
        __half2 ha[NH2], hb[NH2];
        if constexpr (NH2 == 4) {
            uint4 va = *reinterpret_cast<const uint4*>(h + ja * (unsigned)ROWS + chan);
            uint4 vb = *reinterpret_cast<const uint4*>(h + jb * (unsigned)ROWS + chan);
            memcpy(ha, &va, 16);
            memcpy(hb, &vb, 16);
        } else {
            uint2 va = *reinterpret_cast<const uint2*>(h + ja * (unsigned)ROWS + chan);
            uint2 vb = *reinterpret_cast<const uint2*>(h + jb * (unsigned)ROWS + chan);
            memcpy(ha, &va, 8);
            memcpy(hb, &vb, 8);
        }
        float xa = exp2_fast(fmaxf(ta, 0.2f * ta));
        float xb = exp2_fast(fmaxf(tb, 0.2f * tb));
        xa = (k < deg) ? xa : 0.f;
        xb = (k + 1 < deg) ? xb : 0.f;
#pragma unroll
        for (int q = 0; q < NH2; ++q) {
            float2 fa = __half22float2(ha[q]);
            float2 fb = __half22float2(hb[q]);
            acc[q].x = fmaf(xa, fa.x, acc[q].x);
            acc[q].y = fmaf(xa, fa.y, acc[q].y);
            acc[q].x = fmaf(xb, fb.x, acc[q].x);
            acc[q].y = fmaf(xb, fb.y, acc[q].y);
        }
        den += xa + xb;
    }
    float r = 1.0f / (den + 1e-16f);
    if (!live) return;
    const float* bp = bias + chan;
    if constexpr (sizeof(OutT) == 2) {
        __half2 st[NH2];
#pragma unroll
        for (int q = 0; q < NH2; ++q) {
            float v0 = acc[q].x * r + bp[2 * q];
            float v1 = acc[q].y * r + bp[2 * q + 1];
            if constexpr (DOELU) {
                v0 = (v0 > 0.f) ? v0 : expm1f(v0);
                v1 = (v1 > 0.f) ? v1 : expm1f(v1);
            }
            st[q] = __floats2half2_rn(v0, v1);
        }
        if constexpr (NH2 == 4) {
            uint4 v; memcpy(&v, st, 16);
            *reinterpret_cast<uint4*>((__half*)out + node * (unsigned)ROWS + chan) = v;
        } else {
            uint2 v; memcpy(&v, st, 8);
            *reinterpret_cast<uint2*>((__half*)out + node * (unsigned)ROWS + chan) = v;
        }
    } else {
        float vs[CPL];
#pragma unroll
        for (int q = 0; q < NH2; ++q) {
            float v0 = acc[q].x * r + bp[2 * q];
            float v1 = acc[q].y * r + bp[2 * q + 1];
            if constexpr (DOELU) {
                v0 = (v0 > 0.f) ? v0 : expm1f(v0);
                v1 = (v1 > 0.f) ? v1 : expm1f(v1);
            }
            vs[2 * q] = v0;
            vs[2 * q + 1] = v1;
        }
#pragma unroll
        for (int q4 = 0; q4 < CPL; q4 += 4) {
            float4 v = make_float4(vs[q4], vs[q4 + 1], vs[q4 + 2], vs[q4 + 3]);
            *reinterpret_cast<float4*>((float*)out + node * (unsigned)ROWS + chan + q4) = v;
        }
    }
}

// ---------------- launch ----------------

extern "C" void kernel_launch(void* const* d_in, const int* in_sizes, int n_in,
                              void* d_out, int out_size, void* d_ws, size_t ws_size,
                              hipStream_t stream) {
    const float* x      = (const float*)d_in[0];
    const int*   ei     = (const int*)d_in[1];
    const float* W1     = (const float*)d_in[2];
    const float* a_src1 = (const float*)d_in[3];
    const float* a_dst1 = (const float*)d_in[4];
    const float* b1     = (const float*)d_in[5];
    const float* W2     = (const float*)d_in[6];
    const float* a_src2 = (const float*)d_in[7];
    const float* a_dst2 = (const float*)d_in[8];
    const float* b2     = (const float*)d_in[9];
    float* out = (float*)d_out;

    const int N = out_size / 64;          // 100000
    const int E = in_sizes[1] / 2;        // 1600000
    const int Etot = E + N;

    size_t off = 0;
    auto carve = [&](size_t bytes) -> void* {
        void* p = (char*)d_ws + off;
        off += (bytes + 255) & ~(size_t)255;
        return p;
    };
    __half* h1      = (__half*)carve((size_t)N * 128 * 2);   // fp16 h, layer 1
    __half* hmid    = (__half*)carve((size_t)N * 128 * 2);   // fp16 ELU output
    float* as1      = (float*)carve((size_t)N * 4 * 4);
    float* ad1      = (float*)carve((size_t)N * 4 * 4);
    float* as2      = (float*)carve((size_t)N * 4);
    float* ad2      = (float*)carve((size_t)N * 4);
    int*   offs     = (int*)carve((size_t)(N + 1) * 4);
    int*   srcs     = (int*)carve((size_t)Etot * 4);
    unsigned* rec   = (unsigned*)carve((size_t)Etot * 4);
    unsigned* bcount  = (unsigned*)carve(NBK * 4);
    unsigned* bbase   = (unsigned*)carve((NBK + 1) * 4);
    unsigned* bcursor = (unsigned*)carve(NBK * 4);
    __half* h2      = h1;    // alias: h1 dead after aggregate1

    // CSR build via bucketed counting sort (shared by both layers)
    hipMemsetAsync(bcount, 0, NBK * sizeof(unsigned), stream);
    bucket_hist<<<128, 256, 0, stream>>>(ei, E, N, bcount);
    scan_buckets<<<1, 256, 0, stream>>>(bcount, bbase, bcursor);
    bucket_scatter<<<(Etot + CH1 - 1) / CH1, 256, 0, stream>>>(ei, E, N, bcursor, rec);
    bucket_sort<<<(N + DPB - 1) / DPB, 256, 0, stream>>>(rec, bbase, offs, srcs, N, Etot);

    // Layer 1 (alphas fused into gemm epilogue); aggregation in 2 half-channel passes
    gemm_k128<128, 4, float, __half><<<(N + 63) / 64, 256, 0, stream>>>(
        x, W1, h1, a_src1, a_dst1, as1, ad1, N);
    aggregateQ<4, 128, 0, 64, true, __half><<<(N + 15) / 16, 256, 0, stream>>>(
        h1, as1, ad1, offs, srcs, b1, hmid, N);
    aggregateQ<4, 128, 64, 64, true, __half><<<(N + 15) / 16, 256, 0, stream>>>(
        h1, as1, ad1, offs, srcs, b1, hmid, N);

    // Layer 2
    gemm_k128<64, 1, __half, __half><<<(N + 63) / 64, 256, 0, stream>>>(
        hmid, W2, h2, a_src2, a_dst2, as2, ad2, N);
    aggregateQ<1, 64, 0, 64, false, float><<<(N + 15) / 16, 256, 0, stream>>>(
        h2, as2, ad2, offs, srcs, b2, out, N);
}

// Round 8
// 383.872 us; speedup vs baseline: 1.0838x; 1.0838x over previous
//
#include <hip/hip_runtime.h>
#include <hip/hip_fp16.h>
#include <math.h>
#include <string.h>

// GAT 2-layer, N=100000, E=1600000, F_IN=128, HID=128 (H=4,C=32), OUT=64 (H=1,C=64)
// R7 -> R8: (1) revert aggregation to single full-channel pass (R7 proved the
// gather is line-request-bound: half-channels gave same total FETCH, +30us of
// duplicated work). (2) GEMMs -> MFMA fp16 (v_mfma_f32_16x16x32_f16), no LDS:
// A-frag 16B/lane from global, B-frag from pre-transposed fp16 W^T (L2-hot),
// alphas fused via 16-lane shfl in epilogue. Verified lane maps: A[m=lane&15]
// [k=quad*8+j], B[k=quad*8+j][n=lane&15], D[row=quad*4+reg][col=lane&15].

#define BSH 9      // log2 dsts per bucket
#define DPB 512    // dsts per bucket
#define NBK 256    // max buckets (covers N < 131072)
#define CH1 16384  // edges per block in bucket_scatter
#define LOG2E 1.44269504088896f

using half8 = __attribute__((ext_vector_type(8))) _Float16;
using floatx4 = __attribute__((ext_vector_type(4))) float;

__device__ __forceinline__ float exp2_fast(float x) {
#if __has_builtin(__builtin_amdgcn_exp2f)
    return __builtin_amdgcn_exp2f(x);
#else
    return exp2f(x);
#endif
}

// ---------------- CSR build: bucketed counting sort ----------------

__global__ __launch_bounds__(256) void bucket_hist(const int* __restrict__ ei, int E, int N,
                                                   unsigned* __restrict__ bcount) {
    __shared__ unsigned hist[NBK];
    int t = threadIdx.x;
    hist[t] = 0;
    __syncthreads();
    int Etot = E + N;
    for (int k = blockIdx.x * 256 + t; k < Etot; k += gridDim.x * 256) {
        int d = (k < E) ? ei[E + k] : (k - E);
        atomicAdd(&hist[d >> BSH], 1u);
    }
    __syncthreads();
    unsigned c = hist[t];
    if (c) atomicAdd(&bcount[t], c);
}

__global__ void scan_buckets(const unsigned* __restrict__ bcount, unsigned* __restrict__ bbase,
                             unsigned* __restrict__ bcursor) {
    __shared__ unsigned s[NBK];
    int t = threadIdx.x;
    unsigned v = bcount[t];
    s[t] = v;
    __syncthreads();
    for (int o = 1; o < NBK; o <<= 1) {
        unsigned add = (t >= o) ? s[t - o] : 0;
        __syncthreads();
        s[t] += add;
        __syncthreads();
    }
    unsigned excl = s[t] - v;
    bbase[t] = excl;
    bcursor[t] = excl;
    if (t == NBK - 1) bbase[NBK] = excl + v;   // = Etot
}

// rec word: src in bits [0,17), dst low 9 bits in [17,26)
__global__ __launch_bounds__(256) void bucket_scatter(const int* __restrict__ ei, int E, int N,
                                                      unsigned* __restrict__ bcursor,
                                                      unsigned* __restrict__ rec) {
    __shared__ unsigned hist[NBK];
    __shared__ unsigned base[NBK];
    int t = threadIdx.x;
    hist[t] = 0;
    __syncthreads();
    int Etot = E + N;
    int k0 = blockIdx.x * CH1;
    int k1 = min(k0 + CH1, Etot);
    for (int k = k0 + t; k < k1; k += 256) {
        int d = (k < E) ? ei[E + k] : (k - E);
        atomicAdd(&hist[d >> BSH], 1u);
    }
    __syncthreads();
    unsigned c = hist[t];
    base[t] = c ? atomicAdd(&bcursor[t], c) : 0u;
    hist[t] = 0;
    __syncthreads();
    for (int k = k0 + t; k < k1; k += 256) {
        int s, d;
        if (k < E) { s = ei[k]; d = ei[E + k]; } else { s = d = k - E; }
        int b = d >> BSH;
        unsigned r = atomicAdd(&hist[b], 1u);
        rec[base[b] + r] = (unsigned)s | ((unsigned)(d & (DPB - 1)) << 17);
    }
}

__global__ __launch_bounds__(256) void bucket_sort(const unsigned* __restrict__ rec,
                                                   const unsigned* __restrict__ bbase,
                                                   int* __restrict__ offs, int* __restrict__ srcs,
                                                   int N, int Etot) {
    __shared__ unsigned hist[DPB];
    __shared__ unsigned tsum[256];
    int t = threadIdx.x, bb = blockIdx.x;
    unsigned r0 = bbase[bb], r1 = bbase[bb + 1];
    hist[t] = 0;
    hist[t + 256] = 0;
    __syncthreads();
    int dlo = bb << BSH;
    for (unsigned k = r0 + t; k < r1; k += 256) {
        unsigned e = rec[k];
        atomicAdd(&hist[e >> 17], 1u);
    }
    __syncthreads();
    unsigned h0 = hist[2 * t], h1 = hist[2 * t + 1];
    tsum[t] = h0 + h1;
    __syncthreads();
    for (int o = 1; o < 256; o <<= 1) {
        unsigned a = (t >= o) ? tsum[t - o] : 0;
        __syncthreads();
        tsum[t] += a;
        __syncthreads();
    }
    unsigned tb = tsum[t] - (h0 + h1);
    int d0 = dlo + 2 * t;
    if (d0 < N) offs[d0] = (int)(r0 + tb);
    if (d0 + 1 < N) offs[d0 + 1] = (int)(r0 + tb + h0);
    hist[2 * t] = tb;            // reuse as relative cursors
    hist[2 * t + 1] = tb + h0;
    __syncthreads();
    for (unsigned k = r0 + t; k < r1; k += 256) {
        unsigned e = rec[k];
        unsigned r = atomicAdd(&hist[e >> 17], 1u);
        srcs[r0 + r] = (int)(e & 0x1FFFFu);
    }
    if (bb == 0 && t == 0) offs[N] = Etot;
}

// ---------------- weight transpose to fp16: Wt[n*128 + k] = W[k*Nc + n] ----------------

__global__ void transpose_w(const float* __restrict__ W, __half* __restrict__ Wt,
                            int K, int Nc) {
    int idx = blockIdx.x * 256 + threadIdx.x;
    if (idx >= K * Nc) return;
    int n = idx / K, k = idx - n * K;
    Wt[n * K + k] = __float2half(W[k * Nc + n]);
}

// ---------------- MFMA GEMM + fused alphas ----------------
// C[M,NC] = A[M,128] * W[128,NC]; W passed pre-transposed fp16 Wt[NC][128].
// Block = 256 thr = 4 waves; wave computes 16 rows x NC cols, no LDS.
// Epilogue: fp16 C store + as/ad = (C . a_src/a_dst) per head, 16-lane shfl.

template <int NC, int H, typename InT>
__global__ __launch_bounds__(256) void gemm_mfma(const InT* __restrict__ A,
                                                 const __half* __restrict__ Wt,
                                                 __half* __restrict__ C,
                                                 const float* __restrict__ a_src,
                                                 const float* __restrict__ a_dst,
                                                 float* __restrict__ as,
                                                 float* __restrict__ ad, int M) {
    constexpr int NT = NC / 16;      // col tiles (8 or 4)
    constexpr int TPH = NT / H;      // tiles per head (2 or 4)
    int wave = threadIdx.x >> 6;
    int lane = threadIdx.x & 63;
    int quad = lane >> 4, col = lane & 15;
    int row0 = blockIdx.x * 64 + wave * 16;
    int arow = row0 + col;           // A fragment row (m = lane&15)
    if (arow >= M) arow = M - 1;
    floatx4 acc[NT] = {};
    const __half* wp = Wt + col * 128 + quad * 8;   // + t*16*128 + k0 per step
#pragma unroll
    for (int k0 = 0; k0 < 128; k0 += 32) {
        half8 af;
        if constexpr (sizeof(InT) == 4) {
            const float* ap = (const float*)A + (size_t)arow * 128 + k0 + quad * 8;
            float4 v0 = *reinterpret_cast<const float4*>(ap);
            float4 v1 = *reinterpret_cast<const float4*>(ap + 4);
            af[0] = (_Float16)v0.x; af[1] = (_Float16)v0.y;
            af[2] = (_Float16)v0.z; af[3] = (_Float16)v0.w;
            af[4] = (_Float16)v1.x; af[5] = (_Float16)v1.y;
            af[6] = (_Float16)v1.z; af[7] = (_Float16)v1.w;
        } else {
            af = *reinterpret_cast<const half8*>((const __half*)A + (size_t)arow * 128 + k0 + quad * 8);
        }
#pragma unroll
        for (int t = 0; t < NT; ++t) {
            half8 bf = *reinterpret_cast<const half8*>(wp + t * 16 * 128 + k0);
            acc[t] = __builtin_amdgcn_mfma_f32_16x16x32_f16(af, bf, acc[t], 0, 0, 0);
        }
    }
    // epilogue
    float sa[NT], da[NT];
#pragma unroll
    for (int t = 0; t < NT; ++t) {
        sa[t] = a_src[t * 16 + col];
        da[t] = a_dst[t * 16 + col];
    }
    int rbase = row0 + quad * 4;
#pragma unroll
    for (int reg = 0; reg < 4; ++reg) {
        int row = rbase + reg;
        bool live = row < M;
        if (live) {
#pragma unroll
            for (int t = 0; t < NT; ++t)
                C[(size_t)row * NC + t * 16 + col] = __float2half(acc[t][reg]);
        }
#pragma unroll
        for (int h = 0; h < H; ++h) {
            float ps = 0.f, pd = 0.f;
#pragma unroll
            for (int tt = 0; tt < TPH; ++tt) {
                int t = h * TPH + tt;
                ps = fmaf(acc[t][reg], sa[t], ps);
                pd = fmaf(acc[t][reg], da[t], pd);
            }
#pragma unroll
            for (int o = 1; o < 16; o <<= 1) {
                ps += __shfl_xor(ps, o, 64);
                pd += __shfl_xor(pd, o, 64);
            }
            if (col == 0 && live) {
                as[(size_t)row * H + h] = ps * LOG2E;
                ad[(size_t)row * H + h] = pd * LOG2E;
            }
        }
    }
}

// ---------------- aggregation: 4 dst nodes per wave, 16 lanes per node ----------------

template <int H, int ROWS, int CW, bool DOELU, typename OutT>
__global__ __launch_bounds__(256) void aggregateQ(const __half* __restrict__ h,
                                                  const float* __restrict__ as,
                                                  const float* __restrict__ ad,
                                                  const int* __restrict__ offs,
                                                  const int* __restrict__ srcs,
                                                  const float* __restrict__ bias,
                                                  OutT* __restrict__ out, int N) {
    constexpr int CPL = CW / 16;    // channels per lane (8 or 4)
    constexpr int NH2 = CPL / 2;    // half2 per lane
    unsigned wave = (blockIdx.x * blockDim.x + threadIdx.x) >> 6;
    unsigned lane = threadIdx.x & 63;
    unsigned lig = lane & 15;       // lane in group
    unsigned node = wave * 4u + (lane >> 4);
    bool live = node < (unsigned)N;
    unsigned nc = live ? node : (unsigned)(N - 1);
    unsigned chan = lig * CPL;
    unsigned head = (chan * H) / ROWS;
    float adv = ad[nc * H + head];
    int e0 = offs[nc], e1 = offs[nc + 1];
    int deg = e1 - e0, e1m1 = e1 - 1;
    int md = deg;
    md = max(md, __shfl_xor(md, 16, 64));
    md = max(md, __shfl_xor(md, 32, 64));
    float2 acc[NH2] = {};
    float den = 0.f;
    for (int k = 0; k < md; k += 2) {
        unsigned ja = (unsigned)srcs[min(e0 + k, e1m1)];
        unsigned jb = (unsigned)srcs[min(e0 + k + 1, e1m1)];
        float ta = as[ja * H + head] + adv;
        float tb = as[jb * H + head] + adv;
        __half2 ha[NH2], hb[NH2];
        if constexpr (NH2 == 4) {
            uint4 va = *reinterpret_cast<const uint4*>(h + ja * (unsigned)ROWS + chan);
            uint4 vb = *reinterpret_cast<const uint4*>(h + jb * (unsigned)ROWS + chan);
            memcpy(ha, &va, 16);
            memcpy(hb, &vb, 16);
        } else {
            uint2 va = *reinterpret_cast<const uint2*>(h + ja * (unsigned)ROWS + chan);
            uint2 vb = *reinterpret_cast<const uint2*>(h + jb * (unsigned)ROWS + chan);
            memcpy(ha, &va, 8);
            memcpy(hb, &vb, 8);
        }
        float xa = exp2_fast(fmaxf(ta, 0.2f * ta));
        float xb = exp2_fast(fmaxf(tb, 0.2f * tb));
        xa = (k < deg) ? xa : 0.f;
        xb = (k + 1 < deg) ? xb : 0.f;
#pragma unroll
        for (int q = 0; q < NH2; ++q) {
            float2 fa = __half22float2(ha[q]);
            float2 fb = __half22float2(hb[q]);
            acc[q].x = fmaf(xa, fa.x, acc[q].x);
            acc[q].y = fmaf(xa, fa.y, acc[q].y);
            acc[q].x = fmaf(xb, fb.x, acc[q].x);
            acc[q].y = fmaf(xb, fb.y, acc[q].y);
        }
        den += xa + xb;
    }
    float r = 1.0f / (den + 1e-16f);
    if (!live) return;
    const float* bp = bias + chan;
    if constexpr (sizeof(OutT) == 2) {
        __half2 st[NH2];
#pragma unroll
        for (int q = 0; q < NH2; ++q) {
            float v0 = acc[q].x * r + bp[2 * q];
            float v1 = acc[q].y * r + bp[2 * q + 1];
            if constexpr (DOELU) {
                v0 = (v0 > 0.f) ? v0 : expm1f(v0);
                v1 = (v1 > 0.f) ? v1 : expm1f(v1);
            }
            st[q] = __floats2half2_rn(v0, v1);
        }
        if constexpr (NH2 == 4) {
            uint4 v; memcpy(&v, st, 16);
            *reinterpret_cast<uint4*>((__half*)out + node * (unsigned)ROWS + chan) = v;
        } else {
            uint2 v; memcpy(&v, st, 8);
            *reinterpret_cast<uint2*>((__half*)out + node * (unsigned)ROWS + chan) = v;
        }
    } else {
        float vs[CPL];
#pragma unroll
        for (int q = 0; q < NH2; ++q) {
            float v0 = acc[q].x * r + bp[2 * q];
            float v1 = acc[q].y * r + bp[2 * q + 1];
            if constexpr (DOELU) {
                v0 = (v0 > 0.f) ? v0 : expm1f(v0);
                v1 = (v1 > 0.f) ? v1 : expm1f(v1);
            }
            vs[2 * q] = v0;
            vs[2 * q + 1] = v1;
        }
#pragma unroll
        for (int q4 = 0; q4 < CPL; q4 += 4) {
            float4 v = make_float4(vs[q4], vs[q4 + 1], vs[q4 + 2], vs[q4 + 3]);
            *reinterpret_cast<float4*>((float*)out + node * (unsigned)ROWS + chan + q4) = v;
        }
    }
}

// ---------------- launch ----------------

extern "C" void kernel_launch(void* const* d_in, const int* in_sizes, int n_in,
                              void* d_out, int out_size, void* d_ws, size_t ws_size,
                              hipStream_t stream) {
    const float* x      = (const float*)d_in[0];
    const int*   ei     = (const int*)d_in[1];
    const float* W1     = (const float*)d_in[2];
    const float* a_src1 = (const float*)d_in[3];
    const float* a_dst1 = (const float*)d_in[4];
    const float* b1     = (const float*)d_in[5];
    const float* W2     = (const float*)d_in[6];
    const float* a_src2 = (const float*)d_in[7];
    const float* a_dst2 = (const float*)d_in[8];
    const float* b2     = (const float*)d_in[9];
    float* out = (float*)d_out;

    const int N = out_size / 64;          // 100000
    const int E = in_sizes[1] / 2;        // 1600000
    const int Etot = E + N;

    size_t off = 0;
    auto carve = [&](size_t bytes) -> void* {
        void* p = (char*)d_ws + off;
        off += (bytes + 255) & ~(size_t)255;
        return p;
    };
    __half* h1      = (__half*)carve((size_t)N * 128 * 2);   // fp16 h, layer 1
    __half* hmid    = (__half*)carve((size_t)N * 128 * 2);   // fp16 ELU output
    float* as1      = (float*)carve((size_t)N * 4 * 4);
    float* ad1      = (float*)carve((size_t)N * 4 * 4);
    float* as2      = (float*)carve((size_t)N * 4);
    float* ad2      = (float*)carve((size_t)N * 4);
    int*   offs     = (int*)carve((size_t)(N + 1) * 4);
    int*   srcs     = (int*)carve((size_t)Etot * 4);
    unsigned* rec   = (unsigned*)carve((size_t)Etot * 4);
    unsigned* bcount  = (unsigned*)carve(NBK * 4);
    unsigned* bbase   = (unsigned*)carve((NBK + 1) * 4);
    unsigned* bcursor = (unsigned*)carve(NBK * 4);
    __half* Wt1h    = (__half*)carve(128 * 128 * 2);
    __half* Wt2h    = (__half*)carve(64 * 128 * 2);
    __half* h2      = h1;    // alias: h1 dead after aggregate1

    // CSR build via bucketed counting sort (shared by both layers)
    hipMemsetAsync(bcount, 0, NBK * sizeof(unsigned), stream);
    bucket_hist<<<128, 256, 0, stream>>>(ei, E, N, bcount);
    scan_buckets<<<1, 256, 0, stream>>>(bcount, bbase, bcursor);
    bucket_scatter<<<(Etot + CH1 - 1) / CH1, 256, 0, stream>>>(ei, E, N, bcursor, rec);
    bucket_sort<<<(N + DPB - 1) / DPB, 256, 0, stream>>>(rec, bbase, offs, srcs, N, Etot);

    // fp16 transposed weights (tiny, once per launch)
    transpose_w<<<64, 256, 0, stream>>>(W1, Wt1h, 128, 128);
    transpose_w<<<32, 256, 0, stream>>>(W2, Wt2h, 128, 64);

    // Layer 1: MFMA gemm (alphas fused) + single-pass aggregation
    gemm_mfma<128, 4, float><<<(N + 63) / 64, 256, 0, stream>>>(
        x, Wt1h, h1, a_src1, a_dst1, as1, ad1, N);
    aggregateQ<4, 128, 128, true, __half><<<(N + 15) / 16, 256, 0, stream>>>(
        h1, as1, ad1, offs, srcs, b1, hmid, N);

    // Layer 2
    gemm_mfma<64, 1, __half><<<(N + 63) / 64, 256, 0, stream>>>(
        hmid, Wt2h, h2, a_src2, a_dst2, as2, ad2, N);
    aggregateQ<1, 64, 64, false, float><<<(N + 15) / 16, 256, 0, stream>>>(
        h2, as2, ad2, offs, srcs, b2, out, N);
}